// Round 3
// baseline (203.587 us; speedup 1.0000x reference)
//
#include <hip/hip_runtime.h>

typedef unsigned short ushort_t;
typedef unsigned int uint32;
typedef __attribute__((ext_vector_type(8))) short s16x8;   // 8 bf16 in 4 VGPRs
typedef __attribute__((ext_vector_type(4))) float f32x4;   // MFMA accumulator

#define BB   16
#define CC   256
#define NPX  4096          // 64*64 pixels
#define EE   4
#define HID  128
#define RHH  128
#define PW   66            // padded image width
#define PPX  (66*66)       // padded pixels per image

__device__ __forceinline__ ushort_t f2bf(float f) {
  uint32 x = __float_as_uint(f);
  x += 0x7fffu + ((x >> 16) & 1u);           // round-to-nearest-even
  return (ushort_t)(x >> 16);
}
// async global->LDS, 16B per lane; lds ptr wave-uniform (HW adds lane*16)
__device__ __forceinline__ void g2l16(const void* g, void* l) {
  __builtin_amdgcn_global_load_lds((const __attribute__((address_space(1))) uint32*)g,
                                   (__attribute__((address_space(3))) uint32*)l, 16, 0, 0);
}

#define LGKM0  asm volatile("s_waitcnt lgkmcnt(0)" ::: "memory")
#define SBAR   __builtin_amdgcn_s_barrier()
#define SCHED0 __builtin_amdgcn_sched_barrier(0)

// ---------- prep: pooling + weight prep (incl Wr1 transpose) + y1 pad ring ----------
__global__ __launch_bounds__(256)
void k_prep(const float* __restrict__ x, float* __restrict__ pooled,
            const float* __restrict__ W1f, const float* __restrict__ W3f,
            const float* __restrict__ W2f, const float* __restrict__ Wr1,
            ushort_t* __restrict__ W1b, ushort_t* __restrict__ W3b,
            ushort_t* __restrict__ W2r, float* __restrict__ Wr1T,
            ushort_t* __restrict__ y1Tp) {
  int bid = blockIdx.x, t = threadIdx.x;
  if (bid < 4096) {           // pooling: one block per (b,c), 16KB contiguous read
    int c = bid & 255, b = bid >> 8;
    const float* xg = x + ((size_t)b * CC + c) * NPX;
    float s = 0.f;
#pragma unroll
    for (int k = 0; k < 4; ++k) {
      float4 v = *(const float4*)(xg + (size_t)(k * 256 + t) * 4);
      s += v.x + v.y + v.z + v.w;
    }
#pragma unroll
    for (int o = 32; o >= 1; o >>= 1) s += __shfl_down(s, o, 64);
    __shared__ float wsum[4];
    if ((t & 63) == 0) wsum[t >> 6] = s;
    __syncthreads();
    if (t == 0) pooled[(size_t)b * CC + c] = wsum[0] + wsum[1] + wsum[2] + wsum[3];
  } else if (bid < 4352) {    // W1/W3 convert, 4 elems/thread
    int i4 = ((bid - 4096) * 256 + t) * 4;
    const float* src; ushort_t* dst; int off;
    if (i4 < EE * HID * CC) { src = W1f; dst = W1b; off = i4; }
    else { src = W3f; dst = W3b; off = i4 - EE * HID * CC; }
    float4 v = *(const float4*)(src + off);
    ushort4 o;
    o.x = f2bf(v.x); o.y = f2bf(v.y); o.z = f2bf(v.z); o.w = f2bf(v.w);
    *(ushort4*)(dst + off) = o;
  } else if (bid < 4480) {    // W2 repack: contiguous 72B reads, u32 coalesced stores
    int idx = (bid - 4352) * 256 + t;     // 0..32767 = (e*128+o)*64 + ip/2
    int e = idx >> 13;
    int o = (idx >> 6) & 127;
    int ip = (idx & 63) * 2;
    const float* s0 = W2f + ((size_t)((e * 128 + o) * 128) + ip) * 9;
    float v0[9], v1[9];
#pragma unroll
    for (int tp = 0; tp < 9; ++tp) { v0[tp] = s0[tp]; v1[tp] = s0[9 + tp]; }
#pragma unroll
    for (int tp = 0; tp < 9; ++tp) {
      uint32 w = (uint32)f2bf(v0[tp]) | ((uint32)f2bf(v1[tp]) << 16);
      *(uint32*)&W2r[(((size_t)(e * 9 + tp) * 128 + o) * 128) + ip] = w;
    }
  } else if (bid < 4512) {    // Wr1 transpose: [128rh][256c] -> [256c][128rh]
    int i4 = ((bid - 4480) * 256 + t) * 4;
    int rh = i4 >> 8, c = i4 & 255;
    float4 v = *(const float4*)(Wr1 + i4);
    Wr1T[(size_t)(c + 0) * RHH + rh] = v.x;
    Wr1T[(size_t)(c + 1) * RHH + rh] = v.y;
    Wr1T[(size_t)(c + 2) * RHH + rh] = v.z;
    Wr1T[(size_t)(c + 3) * RHH + rh] = v.w;
  } else {                    // y1 pad ring: 260 pad px/batch, 128ch, zero
    int p = (bid - 4512) * 8 + (t >> 5);      // pad-pixel index, 32 lanes each
    int b = p / 260, i = p % 260;
    int row, col;
    if (i < 66)       { row = 0;       col = i; }
    else if (i < 132) { row = 65;      col = i - 66; }
    else if (i < 196) { row = i - 131; col = 0; }
    else              { row = i - 195; col = 65; }
    uint2* dst = (uint2*)(y1Tp + (((size_t)b * PPX + row * PW + col) * HID) + (t & 31) * 4);
    *dst = make_uint2(0u, 0u);
  }
}

// BK=64 tile staging: rows are 128B; 16B chunks XOR-swizzled (chunk^row&7) so
// ds_read_b128 fragment reads spread across banks. Swizzle applied on the
// GLOBAL address side of global_load_lds (its LDS side is fixed lane*16).
#define STAGE64B(dstB, srcB_expr)                                         \
  {                                                                       \
    _Pragma("unroll")                                                     \
    for (int s_ = 0; s_ < 4; ++s_) {                                      \
      int ch_ = wave * 4 + s_;                                            \
      int r = ch_ * 8 + (lane >> 3);                                      \
      int kc = ((lane & 7) ^ (lane >> 3)) * 8;                            \
      g2l16(srcB_expr, &dstB[ch_ * 512]);                                 \
    }                                                                     \
  }

// weight-tile stage: 128 rows x 64 k from wsrc (row stride HID), k offset k0v
#define STAGEW(dst, wsrc, k0v)                                            \
  {                                                                       \
    _Pragma("unroll")                                                     \
    for (int s_ = 0; s_ < 4; ++s_) {                                      \
      int ch_ = wave * 4 + s_;                                            \
      int r_ = ch_ * 8 + (lane >> 3);                                     \
      int kc_ = ((lane & 7) ^ (lane >> 3)) * 8;                           \
      g2l16(wsrc + (size_t)r_ * HID + (k0v) + kc_, &dst[ch_ * 512]);      \
    }                                                                     \
  }

#define MFMA64(At_, Bt_, ACC_)                                            \
  _Pragma("unroll")                                                       \
  for (int kh = 0; kh < 2; ++kh) {                                        \
    s16x8 af[4], bfr[4];                                                  \
    int cidx = ((kh * 4 + (lane >> 4)) ^ (lane & 7)) * 8;                 \
    _Pragma("unroll")                                                     \
    for (int i = 0; i < 4; ++i)                                           \
      af[i] = *(const s16x8*)&At_[(wm + i * 16 + (lane & 15)) * 64 + cidx]; \
    _Pragma("unroll")                                                     \
    for (int j = 0; j < 4; ++j)                                           \
      bfr[j] = *(const s16x8*)&Bt_[(wn + j * 16 + (lane & 15)) * 64 + cidx]; \
    _Pragma("unroll")                                                     \
    for (int i = 0; i < 4; ++i)                                           \
      _Pragma("unroll")                                                   \
      for (int j = 0; j < 4; ++j)                                         \
        ACC_[i][j] = __builtin_amdgcn_mfma_f32_16x16x32_bf16(af[i], bfr[j], ACC_[i][j], 0, 0, 0); \
  }

// A from resident halo Hs[4][66][64] (pixel-major, chunk-XOR key = pixidx&7)
#define MFMA64H(Hs_, dyv, dxv, Bt_, ACC_)                                 \
  {                                                                       \
    int hbase = ((wm >> 6) + 1 + (dyv)) * 66 + (lane & 15) + 1 + (dxv);   \
    _Pragma("unroll")                                                     \
    for (int kh = 0; kh < 2; ++kh) {                                      \
      s16x8 af[4], bfr[4];                                                \
      int clog = kh * 4 + (lane >> 4);                                    \
      int aoff = (clog ^ (hbase & 7)) << 3;                               \
      int cidx = (clog ^ (lane & 7)) << 3;                                \
      _Pragma("unroll")                                                   \
      for (int i = 0; i < 4; ++i)                                         \
        af[i] = *(const s16x8*)&Hs_[(hbase + i * 16) * 64 + aoff];        \
      _Pragma("unroll")                                                   \
      for (int j = 0; j < 4; ++j)                                         \
        bfr[j] = *(const s16x8*)&Bt_[(wn + j * 16 + (lane & 15)) * 64 + cidx]; \
      _Pragma("unroll")                                                   \
      for (int i = 0; i < 4; ++i)                                         \
        _Pragma("unroll")                                                 \
        for (int j = 0; j < 4; ++j)                                       \
          ACC_[i][j] = __builtin_amdgcn_mfma_f32_16x16x32_bf16(af[i], bfr[j], ACC_[i][j], 0, 0, 0); \
    }                                                                     \
  }

// inline router: pooled row -> (e, gw); scratch = 392 floats in LDS.
// Uses lgkm-only barriers so in-flight global_load_lds DMA stays outstanding.
__device__ __forceinline__ void router_inline(
    const float* __restrict__ pooled, const float* __restrict__ Wr1T,
    const float* __restrict__ br1, const float* __restrict__ Wr2,
    const float* __restrict__ br2, float* scratch, int b, int t,
    int* e_out, float* gw_out) {
  float* spool = scratch;            // 256
  float* hbp   = spool + 256;        // 128
  float* lgp   = hbp + 128;          // 4
  float* gwp   = lgp + 4;            // 1
  int*   eip   = (int*)(gwp + 1);    // 1
  if (t < 64) ((float4*)spool)[t] = ((const float4*)(pooled + (size_t)b * CC))[t];
  LGKM0; SBAR; SCHED0;
  if (t < RHH) {
    float aa = 0.f;
    for (int c = 0; c < CC; ++c) aa += spool[c] * Wr1T[(size_t)c * RHH + t];
    float av = br1[t] + aa * (1.0f / NPX);
    hbp[t] = av > 0.f ? av : 0.f;
  }
  LGKM0; SBAR; SCHED0;
  if (t < EE) {
    float sv = br2[t];
    const float* w2 = Wr2 + t * RHH;
    for (int r = 0; r < RHH; ++r) sv += hbp[r] * w2[r];
    lgp[t] = sv;
  }
  LGKM0; SBAR; SCHED0;
  if (t == 0) {
    float m = lgp[0]; int mi = 0;
    for (int ee = 1; ee < EE; ++ee) if (lgp[ee] > m) { m = lgp[ee]; mi = ee; }  // first-max tie rule
    float den = 0.f;
    for (int ee = 0; ee < EE; ++ee) den += expf(lgp[ee] - m);
    float v = 1.0f / den;
    *eip = mi; *gwp = v / (v + 1e-9f);
  }
  LGKM0; SBAR; SCHED0;
  *e_out = *eip; *gw_out = *gwp;
}

// ---------- conv1: inline router + fused x-transpose + 1x1 C->HID ----------
__global__ __launch_bounds__(256)
void k_conv1(const float* __restrict__ x, const ushort_t* __restrict__ W1b,
             const float* __restrict__ pooled, const float* __restrict__ Wr1T,
             const float* __restrict__ br1, const float* __restrict__ Wr2,
             const float* __restrict__ br2, ushort_t* __restrict__ y1Tp) {
  int mt = blockIdx.x, b = blockIdx.y;
  int t = threadIdx.x, wave = t >> 6, lane = t & 63;
  int wm = (wave & 1) * 64, wn = (wave >> 1) * 64;
  __shared__ ushort_t smem[128 * 128];     // 32K: At(16K)+Bt(16K); epilogue alias; router scratch
  ushort_t* At = smem;
  ushort_t* Bt = smem + 128 * 64;
  int e; float gw;
  router_inline(pooled, Wr1T, br1, Wr2, br2, (float*)smem, b, t, &e, &gw);
  f32x4 acc[4][4] = {};
  const float* xg = x + (size_t)b * CC * NPX + mt * 128;
  const ushort_t* w1 = W1b + (size_t)e * HID * CC;

  int cp = t >> 3;              // channel-pair 0..31
  int kk = cp * 2;              // k index within 64-wide K tile
  int pxb = (t & 7) * 4;        // px base: lanes 0-7 cover 128B contiguous per row

  for (int ks = 0; ks < 4; ++ks) {
    int k0 = ks * 64;
    __syncthreads();
    STAGE64B(Bt, w1 + (size_t)r * CC + k0 + kc);
    {   // A transpose: 2 c-rows x 16 px fp32 -> bf16x2 -> swizzled ds_write
      const float* r0 = xg + (size_t)(k0 + kk) * NPX;
      const float* r1 = r0 + NPX;
#pragma unroll
      for (int i = 0; i < 4; ++i) {
        int p = pxb + i * 32;
        float4 va = *(const float4*)(r0 + p);
        float4 vb = *(const float4*)(r1 + p);
#pragma unroll
        for (int q = 0; q < 4; ++q) {
          int m = p + q;
          uint32 v = (uint32)f2bf(((const float*)&va)[q]) |
                     ((uint32)f2bf(((const float*)&vb)[q]) << 16);
          int us = m * 64 + (((kk >> 3) ^ (m & 7)) << 3) + (kk & 7);
          *(uint32*)&At[us] = v;
        }
      }
    }
    __syncthreads();
    MFMA64(At, Bt, acc);
  }
  // epilogue: relu+cvt -> swizzled LDS tile -> coalesced 16B/lane y1 writes
  __syncthreads();
#pragma unroll
  for (int i = 0; i < 4; ++i)
#pragma unroll
    for (int j = 0; j < 4; ++j)
#pragma unroll
      for (int r = 0; r < 4; ++r) {
        int m = wm + i * 16 + (lane >> 4) * 4 + r;
        int n = wn + j * 16 + (lane & 15);
        float v = acc[i][j][r];
        smem[m * 128 + (((n >> 3) ^ (m & 7)) << 3) + (n & 7)] = f2bf(v > 0.f ? v : 0.f);
      }
  __syncthreads();
  ushort_t* yb = y1Tp + (size_t)b * PPX * HID;
#pragma unroll
  for (int it = 0; it < 8; ++it) {
    int idx = it * 256 + t;
    int row = idx >> 4, ch = idx & 15;
    int prow = mt * 2 + (row >> 6) + 1, pcol = (row & 63) + 1;
    uint4 v = *(const uint4*)&smem[row * 128 + ((ch ^ (row & 7)) << 3)];
    *(uint4*)(yb + ((size_t)prow * PW + pcol) * HID + ch * 8) = v;
  }
}

// ---------- fused conv2 (3x3) + conv3 (1x1) + gate + residual ----------
// Counted-vmcnt pipeline end-to-end; no full vmem drains after prologue.
__global__ __launch_bounds__(256, 2)
void k_conv23(const ushort_t* __restrict__ y1Tp, const ushort_t* __restrict__ W2r,
              const ushort_t* __restrict__ W3b, const float* __restrict__ x,
              const float* __restrict__ pooled, const float* __restrict__ Wr1T,
              const float* __restrict__ br1, const float* __restrict__ Wr2,
              const float* __restrict__ br2, float* __restrict__ out) {
  int mt = blockIdx.x, b = blockIdx.y;
  int t = threadIdx.x, wave = t >> 6, lane = t & 63;
  int wm = (wave & 1) * 64, wn = (wave >> 1) * 64;
  __shared__ ushort_t Hs[4 * 66 * 64];    // 33.8K: y1 halo (per K-half); y2s/Tf alias
  __shared__ ushort_t Wb0[128 * 64];      // 16K: W2/W3 double-buffer
  __shared__ ushort_t Wb1[128 * 64];      // 16K: W2/W3 double-buffer; router scratch
  const ushort_t* yb = y1Tp + (size_t)b * PPX * HID;

  auto halo_stage = [&](int k0) {   // 2112 16B chunks, pre-swizzled global src
#pragma unroll
    for (int it = 0; it < 9; ++it) {
      if (it < 8 || wave == 0) {
        int q = it * 256 + t;
        int p = q >> 3, slot = q & 7;
        g2l16(yb + ((size_t)(mt * 132 + p)) * HID + k0 + ((slot ^ (p & 7)) << 3),
              &Hs[(it * 256 + wave * 64) * 8]);
      }
    }
  };

  halo_stage(0);                       // async; overlaps router compute
  int e; float gw;
  router_inline(pooled, Wr1T, br1, Wr2, br2, (float*)Wb1, b, t, &e, &gw);
  const ushort_t* w2e = W2r + (size_t)e * 9 * HID * HID;
  const ushort_t* w3  = W3b + (size_t)e * CC * HID;
  STAGEW(Wb0, w2e, 0);                 // tap 0
  __syncthreads();                     // ONLY full drain: halo0 + tap0 landed

  // ---- phase 1: conv2, halo-resident A, dbuf W2, counted vmcnt ----
  f32x4 acc[4][4] = {};
#pragma unroll
  for (int ks = 0; ks < 2; ++ks) {
#pragma unroll
    for (int tap = 0; tap < 9; ++tap) {
      int par = (tap + ks * 9) & 1;
      ushort_t* cur = par ? Wb1 : Wb0;
      ushort_t* nxt = par ? Wb0 : Wb1;
      if (tap < 8)       { STAGEW(nxt, w2e + (size_t)(tap + 1) * HID * HID, ks * 64); }
      else if (ks == 0)  { STAGEW(nxt, w2e, 64); }          // ks=1 tap0 W2
      else               { STAGEW(nxt, w3, 0); }            // conv3 step0 prefetch
      asm volatile("s_waitcnt vmcnt(4)" ::: "memory");      // my tile landed
      SBAR; SCHED0;                                         // everyone's landed
      __builtin_amdgcn_s_setprio(1);
      MFMA64H(Hs, tap / 3 - 1, tap % 3 - 1, cur, acc);
      __builtin_amdgcn_s_setprio(0);
      SBAR;                                                 // reads done before overwrite
    }
    if (ks == 0) halo_stage(64);   // Hs free; landing checked by next vmcnt(4)
  }
  // ---- phase 2: relu+cvt -> swizzled y2 LDS tile (aliases Hs) ----
  ushort_t (*y2s)[128 * 64] = (ushort_t (*)[128 * 64])Hs;
#pragma unroll
  for (int i = 0; i < 4; ++i)
#pragma unroll
    for (int j = 0; j < 4; ++j)
#pragma unroll
      for (int r = 0; r < 4; ++r) {
        int m = wm + i * 16 + (lane >> 4) * 4 + r;
        int n = wn + j * 16 + (lane & 15);
        float v = acc[i][j][r];
        ushort_t bv = f2bf(v > 0.f ? v : 0.f);
        int nn = n & 63;
        ushort_t* buf = (n < 64) ? y2s[0] : y2s[1];   // wave-uniform select
        buf[m * 64 + ((nn >> 3) ^ (m & 7)) * 8 + (nn & 7)] = bv;
      }
  // ---- phase 3: conv3, counted vmcnt (step0 tile pre-staged at ks1-tap8) ----
  f32x4 acc3[2][4][4] = {};
#pragma unroll
  for (int s = 0; s < 4; ++s) {
    ushort_t* cur = (s & 1) ? Wb1 : Wb0;
    ushort_t* nxt = (s & 1) ? Wb0 : Wb1;
    if (s < 3) {
      int s1 = s + 1;
      STAGEW(nxt, w3 + (size_t)((s1 >> 1) * 128) * HID, (s1 & 1) * 64);
      asm volatile("s_waitcnt vmcnt(4)" ::: "memory");
    } else {
      asm volatile("s_waitcnt vmcnt(0)" ::: "memory");
    }
    if (s == 0) LGKM0;              // phase-2 y2s writes visible
    SBAR; SCHED0;
    __builtin_amdgcn_s_setprio(1);
    MFMA64(y2s[s & 1], cur, acc3[s >> 1]);
    __builtin_amdgcn_s_setprio(0);
    SBAR;
  }
  // ---- phase 4: raw-barrier epilogue, x prefetched 1 segment ahead ----
  float* Tf = (float*)Hs;   // 32c x 128px, pitch 132 (16.9 KB)
  const float* xb = x + (size_t)b * CC * NPX + mt * 128;
  f32x4 xpre[4];
#pragma unroll
  for (int it = 0; it < 4; ++it) {
    int idx = it * 256 + t, crow = idx >> 5, p4 = (idx & 31) * 4;
    xpre[it] = *(const f32x4*)(xb + (size_t)crow * NPX + p4);   // (h0,jj0)
  }
#pragma unroll
  for (int s = 0; s < 8; ++s) {
    int h = s >> 2, jj = s & 3;
    if ((wn >> 6) == (jj >> 1)) {     // the 2 waves holding this c-range
      int j0 = (jj & 1) * 2;
#pragma unroll
      for (int jd = 0; jd < 2; ++jd) {
        int cl = jd * 16 + (lane & 15);
#pragma unroll
        for (int i = 0; i < 4; ++i) {
          int pb = wm + i * 16 + (lane >> 4) * 4;
          *(f32x4*)&Tf[cl * 132 + pb] = acc3[h][i][j0 + jd];
        }
      }
    }
    LGKM0; SBAR; SCHED0;              // Tf visible; NO vmcnt drain (stores in flight)
    f32x4 xc[4];
#pragma unroll
    for (int it = 0; it < 4; ++it) xc[it] = xpre[it];
    if (s < 7) {                      // prefetch next segment's x
      int s1 = s + 1, h1 = s1 >> 2, jj1 = s1 & 3;
#pragma unroll
      for (int it = 0; it < 4; ++it) {
        int idx = it * 256 + t, crow = idx >> 5, p4 = (idx & 31) * 4;
        xpre[it] = *(const f32x4*)(xb + (size_t)(h1 * 128 + jj1 * 32 + crow) * NPX + p4);
      }
    }
#pragma unroll
    for (int it = 0; it < 4; ++it) {
      int idx = it * 256 + t, crow = idx >> 5, p4 = (idx & 31) * 4;
      int c = h * 128 + jj * 32 + crow;
      f32x4 vv = *(const f32x4*)&Tf[crow * 132 + p4];
      vv = gw * vv + xc[it];
      __builtin_nontemporal_store(vv, (f32x4*)(out + ((size_t)b * CC + c) * NPX + mt * 128 + p4));
    }
    SBAR;                             // reads consumed before next writers
  }
}

extern "C" void kernel_launch(void* const* d_in, const int* in_sizes, int n_in,
                              void* d_out, int out_size, void* d_ws, size_t ws_size,
                              hipStream_t stream) {
  const float* x   = (const float*)d_in[0];
  const float* Wr1 = (const float*)d_in[1];
  const float* br1 = (const float*)d_in[2];
  const float* Wr2 = (const float*)d_in[3];
  const float* br2 = (const float*)d_in[4];
  const float* W1  = (const float*)d_in[5];
  const float* W2  = (const float*)d_in[6];
  const float* W3  = (const float*)d_in[7];
  float* out = (float*)d_out;

  char* ws = (char*)d_ws;
  float*    pooled = (float*)(ws + 256);               // 16 KB -> 16640
  ushort_t* W1b    = (ushort_t*)(ws + 16640);          // 256 KB -> 278784
  ushort_t* W3b    = (ushort_t*)(ws + 278784);         // 256 KB -> 540928
  ushort_t* W2r    = (ushort_t*)(ws + 540928);         // 1.125 MB -> 1720576
  float*    Wr1T   = (float*)(ws + 1720576);           // 128 KB -> 1851648
  ushort_t* y1Tp   = (ushort_t*)(ws + 1851648);        // 17.0 MB -> ~19.7 MB total

  k_prep  <<<5032, 256, 0, stream>>>(x, pooled, W1, W3, W2, Wr1, W1b, W3b, W2r, Wr1T, y1Tp);
  k_conv1 <<<dim3(32, 16), 256, 0, stream>>>(x, W1b, pooled, Wr1T, br1, Wr2, br2, y1Tp);
  k_conv23<<<dim3(32, 16), 256, 0, stream>>>(y1Tp, W2r, W3b, x, pooled, Wr1T, br1, Wr2, br2, out);
}